// Round 3
// baseline (491.548 us; speedup 1.0000x reference)
//
#include <hip/hip_runtime.h>

#define NN 100000
#define NE 220000
#define HD 128
#define NG 4096
#define NPE 5
#define NB_SCAN ((NN + 255) / 256)   // 391
#define NBX4 ((NN * HD / 4) / 256)   // 12500 (exact)
#define NBW 128                      // prep_w blocks
#define NBD ((2 * NE + 255) / 256)   // 1719
#define NBT ((NN + 63) / 64)         // 1563 tiles per branch
#define LDP 136

typedef unsigned int uint;
typedef unsigned short ushort;
typedef __attribute__((ext_vector_type(8))) short bf16x8;
typedef __attribute__((ext_vector_type(4))) float f32x4;

__device__ __forceinline__ float bf2f(uint u16) {
    return __uint_as_float(u16 << 16);
}
__device__ __forceinline__ ushort f2bf(float f) {
    uint u = __float_as_uint(f);
    u += 0x7fffu + ((u >> 16) & 1u);   // RNE
    return (ushort)(u >> 16);
}

// Fused front: [0,NBX4) compute x/xb (4 feats/thread); then Wcat; then degree.
__global__ void k_front(const int* __restrict__ tok, const float* __restrict__ pe,
                        const float* __restrict__ embed, const float* __restrict__ Wtr,
                        const float* __restrict__ bt,
                        float* __restrict__ x, ushort* __restrict__ xb,
                        const float* __restrict__ W1, const float* __restrict__ Wv1,
                        ushort* __restrict__ Wcat,
                        const int* __restrict__ ei, const int* __restrict__ vei,
                        int* __restrict__ cnt) {
    int b = blockIdx.x;
    if (b < NBX4) {
        int idx = b * 256 + threadIdx.x;        // one float4 of x
        int n = idx >> 5, q = idx & 31;
        int t = tok[n];
        float4 acc = ((const float4*)(embed + (size_t)t * HD))[q];
        float4 bv = ((const float4*)bt)[q];
        acc.x += bv.x; acc.y += bv.y; acc.z += bv.z; acc.w += bv.w;
        const float* pen = pe + n * NPE;
#pragma unroll
        for (int k = 0; k < NPE; ++k) {
            float p = pen[k];
            float4 wv = ((const float4*)(Wtr + k * HD))[q];
            acc.x += p * wv.x; acc.y += p * wv.y;
            acc.z += p * wv.z; acc.w += p * wv.w;
        }
        ((float4*)x)[idx] = acc;
        uint2 pk;
        pk.x = (uint)f2bf(acc.x) | ((uint)f2bf(acc.y) << 16);
        pk.y = (uint)f2bf(acc.z) | ((uint)f2bf(acc.w) << 16);
        ((uint2*)xb)[idx] = pk;
    } else if (b < NBX4 + NBW) {
        int t = (b - NBX4) * 256 + threadIdx.x;   // 32768
        int f = t >> 7, k = t & 127;
        const float* W = (f < HD) ? W1 : Wv1;
        Wcat[t] = f2bf(W[k * HD + (f & 127)]);    // Wcat[f][k] = W[k][f]
    } else {
        int t = (b - NBX4 - NBW) * 256 + threadIdx.x;
        if (t < 2 * NE) {
            int br = t >= NE;
            int e = t - br * NE;
            const int* S = br ? vei : ei;
            atomicAdd(&cnt[br * NN + S[NE + e]], 1);
        }
    }
}

// per-block exclusive scan + dinv (+ y zeroing folded in)
__global__ void k_scan1(const int* __restrict__ cnt, int* __restrict__ off,
                        int* __restrict__ bsum, float* __restrict__ dinv,
                        float* __restrict__ y) {
    __shared__ int s[256];
    int tid = threadIdx.x;
    int gid = blockIdx.x * 256 + tid;
    if (gid < NG) y[gid] = 0.f;
    int br = blockIdx.x / NB_SCAN;
    int blk = blockIdx.x % NB_SCAN;
    int i = blk * 256 + tid;
    int v = (i < NN) ? cnt[br * NN + i] : 0;
    if (i < NN) dinv[br * NN + i] = rsqrtf((float)v + 1.0f);
    s[tid] = v;
    __syncthreads();
    for (int d = 1; d < 256; d <<= 1) {
        int t = (tid >= d) ? s[tid - d] : 0;
        __syncthreads();
        s[tid] += t;
        __syncthreads();
    }
    if (i < NN) off[br * NN + i] = s[tid] - v;
    if (tid == 255) bsum[br * 512 + blk] = s[255];
}

__global__ void k_scan2(int* __restrict__ bsum) {
    __shared__ int s[512];
    int br = blockIdx.x;
    int tid = threadIdx.x;
    int v = (tid < NB_SCAN) ? bsum[br * 512 + tid] : 0;
    s[tid] = v;
    __syncthreads();
    for (int d = 1; d < 512; d <<= 1) {
        int t = (tid >= d) ? s[tid - d] : 0;
        __syncthreads();
        s[tid] += t;
        __syncthreads();
    }
    if (tid < NB_SCAN) bsum[br * 512 + tid] = s[tid] - v;
}

__global__ void k_scan3(int* __restrict__ off, const int* __restrict__ bsum,
                        int* __restrict__ cur) {
    int br = blockIdx.x / NB_SCAN;
    int blk = blockIdx.x % NB_SCAN;
    int i = blk * 256 + threadIdx.x;
    if (i < NN) {
        int o = off[br * NN + i] + bsum[br * 512 + blk];
        off[br * NN + i] = o;
        cur[br * NN + i] = o;
    }
}

// Scatter packed edge record {src, coef, dst, -} — one 16B store per edge.
__global__ void k_scatter(const int* __restrict__ ei, const int* __restrict__ vei,
                          const float* __restrict__ dinv, int* __restrict__ cur,
                          int4* __restrict__ ent) {
    int t = blockIdx.x * blockDim.x + threadIdx.x;
    if (t >= 2 * NE) return;
    int br = t >= NE;
    int e = t - br * NE;
    const int* S = br ? vei : ei;
    int s = S[e], d = S[NE + e];
    int pos = atomicAdd(&cur[br * NN + d], 1);
    int4 rec;
    rec.x = s;
    rec.y = __float_as_int(dinv[br * NN + s] * dinv[br * NN + d]);
    rec.z = d;
    rec.w = 0;
    ent[br * NE + pos] = rec;
}

// Fused aggregate + layer-1 GEMM + epilogue -> z.  Round-3: EDGE-PARALLEL
// aggregation into LDS f32 accumulators (ds atomics).  Block owns 64 nodes;
// its edges are one contiguous CSR range (node-ordered scans).  16 half-waves
// stride edges: broadcast record + coalesced 256B xb row + 4 LDS atomicAdds.
// No per-node latency chains, no degree-tail imbalance.  acc uses a 16B-chunk
// XOR swizzle (chunk ^= nl&7) so both the atomics and the MFMA-phase f32x4
// reads are conflict-free.
__global__ __launch_bounds__(512) void k_agg_gemm(
        const ushort* __restrict__ xb, const ushort* __restrict__ Wcat,
        const float* __restrict__ dinv, const int* __restrict__ off,
        const int4* __restrict__ ent,
        const float* __restrict__ b1, const float* __restrict__ bv1,
        const float* __restrict__ W2, const float* __restrict__ Wv2,
        float* __restrict__ z) {
    __shared__ float acc[64 * 128];   // 32KB, swizzled
    __shared__ float red[8][64];      // 2KB
    int bi = blockIdx.x;
    int br = bi >= NBT;
    int n0 = (bi - br * NBT) * 64;
    int tid = threadIdx.x;
    int hw = tid >> 5, l = tid & 31;

    // ---- init: self-loop term xb[n] * dinv^2 (zeros for n >= NN) ----
#pragma unroll
    for (int r = 0; r < 4; ++r) {
        int nl = r * 16 + hw;
        int n = n0 + nl;
        float4 v = {0.f, 0.f, 0.f, 0.f};
        if (n < NN) {
            float dv = dinv[br * NN + n];
            float c = dv * dv;
            uint2 u = *(const uint2*)(xb + (size_t)n * HD + l * 4);
            v.x = bf2f(u.x & 0xffffu) * c;
            v.y = bf2f(u.x >> 16) * c;
            v.z = bf2f(u.y & 0xffffu) * c;
            v.w = bf2f(u.y >> 16) * c;
        }
        *(float4*)&acc[nl * 128 + ((l ^ (nl & 7)) << 2)] = v;
    }
    __syncthreads();

    // ---- edge-parallel aggregation ----
    {
        int p0 = off[br * NN + n0];
        int p1 = (n0 + 64 < NN) ? off[br * NN + n0 + 64] : NE;
        const int4* E = ent + br * NE;
        int p = p0 + hw;
        int4 r0;
        if (p < p1) r0 = E[p];
        while (p < p1) {
            int pn = p + 16;
            int4 r1;
            if (pn < p1) r1 = E[pn];               // prefetch next record
            int src = r0.x;
            float cf = __int_as_float(r0.y);
            int nl = r0.z - n0;
            uint2 v = *(const uint2*)(xb + (size_t)src * HD + l * 4);
            float* a = &acc[nl * 128 + ((l ^ (nl & 7)) << 2)];
            atomicAdd(a + 0, bf2f(v.x & 0xffffu) * cf);
            atomicAdd(a + 1, bf2f(v.x >> 16) * cf);
            atomicAdd(a + 2, bf2f(v.y & 0xffffu) * cf);
            atomicAdd(a + 3, bf2f(v.y >> 16) * cf);
            r0 = r1;
            p = pn;
        }
    }
    __syncthreads();

    // ---- [64 nodes] x W1 (128x128); wave w owns feats ft = w*16.. ----
    int w = tid >> 6, lane = tid & 63;
    int m = lane & 15, quad = lane >> 4;
    const ushort* Wg = Wcat + (size_t)br * 128 * 128;
    f32x4 a4[4] = {};
#pragma unroll
    for (int kc = 0; kc < 4; ++kc) {
        int k0 = kc * 32 + quad * 8;
        bf16x8 wf = *(const bf16x8*)&Wg[(w * 16 + m) * 128 + k0];
        int c0 = k0 >> 2;
#pragma unroll
        for (int nt = 0; nt < 4; ++nt) {
            int nl = nt * 16 + m;
            const float* rowb = &acc[nl * 128];
            float4 lo = *(const float4*)&rowb[((c0) ^ (nl & 7)) << 2];
            float4 hi = *(const float4*)&rowb[((c0 + 1) ^ (nl & 7)) << 2];
            bf16x8 xf;
            xf[0] = (short)f2bf(lo.x); xf[1] = (short)f2bf(lo.y);
            xf[2] = (short)f2bf(lo.z); xf[3] = (short)f2bf(lo.w);
            xf[4] = (short)f2bf(hi.x); xf[5] = (short)f2bf(hi.y);
            xf[6] = (short)f2bf(hi.z); xf[7] = (short)f2bf(hi.w);
            a4[nt] = __builtin_amdgcn_mfma_f32_16x16x32_bf16(wf, xf, a4[nt], 0, 0, 0);
        }
    }
    // lane holds feats f = w*16 + quad*4 + j for node n0 + nt*16 + m
    const float* bb = br ? bv1 : b1;
    const float* ww = br ? Wv2 : W2;
    int f0 = w * 16 + quad * 4;
    float4 b4 = *(const float4*)&bb[f0];
    float4 w4 = *(const float4*)&ww[f0];
#pragma unroll
    for (int nt = 0; nt < 4; ++nt) {
        f32x4 a = a4[nt];
        float part = fmaxf(a[0] + b4.x, 0.f) * w4.x + fmaxf(a[1] + b4.y, 0.f) * w4.y
                   + fmaxf(a[2] + b4.z, 0.f) * w4.z + fmaxf(a[3] + b4.w, 0.f) * w4.w;
        part += __shfl_xor(part, 16);
        part += __shfl_xor(part, 32);
        if (lane < 16) red[w][nt * 16 + lane] = part;
    }
    __syncthreads();
    if (tid < 64) {
        int n = n0 + tid;
        if (n < NN) {
            float s = 0.f;
#pragma unroll
            for (int i = 0; i < 8; ++i) s += red[i][tid];
            z[br * NN + n] = s;
        }
    }
}

// Layer-2 aggregation + LDS-batched y reduction (batch is sorted).
// Clamped 4-wide z-walk for MLP.
__global__ void k_final2(const float* __restrict__ z, const float* __restrict__ dinv,
                         const int* __restrict__ off, const int* __restrict__ cur,
                         const int4* __restrict__ ent,
                         const float* __restrict__ b2, const float* __restrict__ bv2,
                         const int* __restrict__ batch, float* __restrict__ y) {
    __shared__ float ybuf[256];
    __shared__ int gbase_s;
    int br = blockIdx.x >= NB_SCAN;
    int nb = blockIdx.x - br * NB_SCAN;
    int tid = threadIdx.x;
    ybuf[tid] = 0.f;
    if (tid == 0) gbase_s = batch[nb * 256];
    __syncthreads();
    int gbase = gbase_s;
    int n = nb * 256 + tid;
    if (n < NN) {
        const int4* en = ent + br * NE;
        float dv = dinv[br * NN + n];
        float acc = z[br * NN + n] * dv * dv;
        int p1 = cur[br * NN + n];
        for (int p = off[br * NN + n]; p < p1; p += 4) {
            int4 e0 = en[p], e1 = en[p + 1], e2 = en[p + 2], e3 = en[p + 3];
            int s0 = e0.x;
            int s1 = (p + 1 < p1) ? e1.x : n;
            int s2 = (p + 2 < p1) ? e2.x : n;
            int s3 = (p + 3 < p1) ? e3.x : n;
            float c0 = __int_as_float(e0.y);
            float c1 = (p + 1 < p1) ? __int_as_float(e1.y) : 0.f;
            float c2 = (p + 2 < p1) ? __int_as_float(e2.y) : 0.f;
            float c3 = (p + 3 < p1) ? __int_as_float(e3.y) : 0.f;
            acc += c0 * z[br * NN + s0] + c1 * z[br * NN + s1]
                 + c2 * z[br * NN + s2] + c3 * z[br * NN + s3];
        }
        acc += br ? bv2[0] : b2[0];
        int gi = batch[n] - gbase;
        if (gi < 256) atomicAdd(&ybuf[gi], acc);
        else atomicAdd(&y[batch[n]], acc);
    }
    __syncthreads();
    float v = ybuf[tid];
    if (v != 0.f) atomicAdd(&y[gbase + tid], v);
}

extern "C" void kernel_launch(void* const* d_in, const int* in_sizes, int n_in,
                              void* d_out, int out_size, void* d_ws, size_t ws_size,
                              hipStream_t stream) {
    const int*   tok   = (const int*)d_in[0];
    const float* pe    = (const float*)d_in[1];
    const int*   ei    = (const int*)d_in[2];
    const int*   vei   = (const int*)d_in[3];
    const int*   batch = (const int*)d_in[4];
    const float* embed = (const float*)d_in[5];
    const float* Wtr   = (const float*)d_in[6];
    const float* bt    = (const float*)d_in[7];
    const float* W1    = (const float*)d_in[8];
    const float* b1    = (const float*)d_in[9];
    const float* W2    = (const float*)d_in[10];
    const float* b2    = (const float*)d_in[11];
    const float* Wv1   = (const float*)d_in[12];
    const float* bv1   = (const float*)d_in[13];
    const float* Wv2   = (const float*)d_in[14];
    const float* bv2   = (const float*)d_in[15];

    float* y = (float*)d_out;       // [NG]
    float* x = y + NG;              // [NN*HD], output 1

    char* w = (char*)d_ws;
    ushort* xb   = (ushort*)w;               w += (size_t)NN * HD * 2;
    ushort* Wcat = (ushort*)w;               w += 256 * 128 * 2;
    float*  dinv = (float*)w;                w += 2 * NN * 4;
    float*  z    = (float*)w;                w += 2 * NN * 4;
    int*    cnt  = (int*)w;                  w += 2 * NN * 4;
    int*    off  = (int*)w;                  w += 2 * NN * 4;
    int*    cur  = (int*)w;                  w += 2 * NN * 4;
    int4*   ent  = (int4*)w;                 w += (size_t)(2 * NE + 8) * 16;  // +pad
    int*    bsum = (int*)w;                  w += 2 * 512 * 4;

    hipMemsetAsync(cnt, 0, 2 * NN * sizeof(int), stream);

    k_front<<<NBX4 + NBW + NBD, 256, 0, stream>>>(tok, pe, embed, Wtr, bt, x, xb,
                                                  W1, Wv1, Wcat, ei, vei, cnt);
    k_scan1<<<2 * NB_SCAN, 256, 0, stream>>>(cnt, off, bsum, dinv, y);
    k_scan2<<<2, 512, 0, stream>>>(bsum);
    k_scan3<<<2 * NB_SCAN, 256, 0, stream>>>(off, bsum, cur);
    k_scatter<<<(2 * NE + 255) / 256, 256, 0, stream>>>(ei, vei, dinv, cur, ent);
    k_agg_gemm<<<2 * NBT, 512, 0, stream>>>(xb, Wcat, dinv, off, ent,
                                            b1, bv1, W2, Wv2, z);
    k_final2<<<2 * NB_SCAN, 256, 0, stream>>>(z, dinv, off, cur, ent,
                                              b2, bv2, batch, y);
}

// Round 4
// 243.707 us; speedup vs baseline: 2.0170x; 2.0170x over previous
//
#include <hip/hip_runtime.h>

#define NN 100000
#define NE 220000
#define HD 128
#define NG 4096
#define NPE 5
#define NB_SCAN ((NN + 255) / 256)   // 391
#define NBF ((NN + 127) / 128)       // 782 front/gemm blocks
#define NBW 128                      // Wcat prep blocks
#define NBZ ((2 * NN + 255) / 256)   // 782 cnt-zero blocks
#define NBD ((2 * NE + 255) / 256)   // 1719 edge blocks
#define LDP 136

typedef unsigned int uint;
typedef unsigned short ushort;
typedef __attribute__((ext_vector_type(8))) short bf16x8;
typedef __attribute__((ext_vector_type(4))) float f32x4;

__device__ __forceinline__ float bf2f(uint u16) {
    return __uint_as_float(u16 << 16);
}
__device__ __forceinline__ ushort f2bf(float f) {
    uint u = __float_as_uint(f);
    u += 0x7fffu + ((u >> 16) & 1u);   // RNE
    return (ushort)(u >> 16);
}

// Prep: build Wcat (transposed bf16 W1|Wv1) and zero cnt. Replaces a memset
// dispatch; first kernel in the graph.
__global__ void k_prep0(const float* __restrict__ W1, const float* __restrict__ Wv1,
                        ushort* __restrict__ Wcat, int* __restrict__ cnt) {
    int b = blockIdx.x;
    if (b < NBW) {
        int t = b * 256 + threadIdx.x;   // 32768
        int f = t >> 7, k = t & 127;
        const float* W = (f < HD) ? W1 : Wv1;
        Wcat[t] = f2bf(W[k * HD + (f & 127)]);    // Wcat[f][k] = W[k][f]
    } else {
        int t = (b - NBW) * 256 + threadIdx.x;
        if (t < 2 * NN) cnt[t] = 0;
    }
}

// Fused front+GEMM: [0,NBF) blocks each own 128 nodes: compute x rows
// (embed + pe@Wt + bt), write x, stage bf16 rows in LDS, then the R0 k_gemm
// MFMA phase for BOTH feature halves -> H[n][256].  xb buffer eliminated
// (saves 25.6MB write + 51.2MB read).  Blocks [NBF, NBF+NBD): degree count.
__global__ __launch_bounds__(256) void k_front_gemm(
        const int* __restrict__ tok, const float* __restrict__ pe,
        const float* __restrict__ embed, const float* __restrict__ Wtr,
        const float* __restrict__ bt, float* __restrict__ x,
        const ushort* __restrict__ Wcat, ushort* __restrict__ H,
        const int* __restrict__ ei, const int* __restrict__ vei,
        int* __restrict__ cnt) {
    __shared__ ushort As[128 * LDP];   // 34.8KB
    int b = blockIdx.x;
    if (b < NBF) {
        int tid = threadIdx.x;
        int n0 = b * 128;
        int q = tid & 31;         // float4 quad within a row
        int nlb = tid >> 5;       // 0..7
        // ---- x phase: 16 iterations x 8 nodes ----
        for (int r = 0; r < 16; ++r) {
            int nl = r * 8 + nlb;
            int n = n0 + nl;
            uint2 pk = {0u, 0u};
            if (n < NN) {
                int t = tok[n];
                float4 acc = ((const float4*)(embed + (size_t)t * HD))[q];
                float4 bv = ((const float4*)bt)[q];
                acc.x += bv.x; acc.y += bv.y; acc.z += bv.z; acc.w += bv.w;
                const float* pen = pe + n * NPE;
#pragma unroll
                for (int k = 0; k < NPE; ++k) {
                    float p = pen[k];
                    float4 wv = ((const float4*)(Wtr + k * HD))[q];
                    acc.x += p * wv.x; acc.y += p * wv.y;
                    acc.z += p * wv.z; acc.w += p * wv.w;
                }
                ((float4*)x)[n * 32 + q] = acc;
                pk.x = (uint)f2bf(acc.x) | ((uint)f2bf(acc.y) << 16);
                pk.y = (uint)f2bf(acc.z) | ((uint)f2bf(acc.w) << 16);
            }
            *(uint2*)&As[nl * LDP + q * 4] = pk;
        }
        __syncthreads();
        // ---- GEMM phase (R0 k_gemm indexing), fh looped ----
        int w = tid >> 6, lane = tid & 63;
        int m = lane & 15, quad = lane >> 4;
#pragma unroll
        for (int fh = 0; fh < 2; ++fh) {
            const ushort* Wg = Wcat + (size_t)fh * 128 * 128;
            f32x4 acc[2][8] = {};
#pragma unroll
            for (int kc = 0; kc < 4; ++kc) {
                int k0 = kc * 32 + quad * 8;
                bf16x8 xf[2];
#pragma unroll
                for (int nt = 0; nt < 2; ++nt)
                    xf[nt] = *(const bf16x8*)&As[((w * 2 + nt) * 16 + m) * LDP + k0];
#pragma unroll
                for (int ft = 0; ft < 8; ++ft) {
                    bf16x8 wf = *(const bf16x8*)&Wg[(ft * 16 + m) * 128 + k0];
#pragma unroll
                    for (int nt = 0; nt < 2; ++nt)
                        acc[nt][ft] = __builtin_amdgcn_mfma_f32_16x16x32_bf16(
                            wf, xf[nt], acc[nt][ft], 0, 0, 0);
                }
            }
#pragma unroll
            for (int nt = 0; nt < 2; ++nt) {
                int n = n0 + (w * 2 + nt) * 16 + m;
                if (n >= NN) continue;
#pragma unroll
                for (int ft = 0; ft < 8; ++ft) {
                    f32x4 a = acc[nt][ft];
                    uint2 pk;
                    pk.x = (uint)f2bf(a[0]) | ((uint)f2bf(a[1]) << 16);
                    pk.y = (uint)f2bf(a[2]) | ((uint)f2bf(a[3]) << 16);
                    *(uint2*)&H[(size_t)n * 256 + fh * 128 + ft * 16 + quad * 4] = pk;
                }
            }
        }
    } else {
        int t = (b - NBF) * 256 + threadIdx.x;
        if (t < 2 * NE) {
            int br = t >= NE;
            int e = t - br * NE;
            const int* S = br ? vei : ei;
            atomicAdd(&cnt[br * NN + S[NE + e]], 1);
        }
    }
}

// per-block exclusive scan + dinv (+ y zeroing folded in)
__global__ void k_scan1(const int* __restrict__ cnt, int* __restrict__ off,
                        int* __restrict__ bsum, float* __restrict__ dinv,
                        float* __restrict__ y) {
    __shared__ int s[256];
    int tid = threadIdx.x;
    int gid = blockIdx.x * 256 + tid;
    if (gid < NG) y[gid] = 0.f;
    int br = blockIdx.x / NB_SCAN;
    int blk = blockIdx.x % NB_SCAN;
    int i = blk * 256 + tid;
    int v = (i < NN) ? cnt[br * NN + i] : 0;
    if (i < NN) dinv[br * NN + i] = rsqrtf((float)v + 1.0f);
    s[tid] = v;
    __syncthreads();
    for (int d = 1; d < 256; d <<= 1) {
        int t = (tid >= d) ? s[tid - d] : 0;
        __syncthreads();
        s[tid] += t;
        __syncthreads();
    }
    if (i < NN) off[br * NN + i] = s[tid] - v;
    if (tid == 255) bsum[br * 512 + blk] = s[255];
}

__global__ void k_scan2(int* __restrict__ bsum) {
    __shared__ int s[512];
    int br = blockIdx.x;
    int tid = threadIdx.x;
    int v = (tid < NB_SCAN) ? bsum[br * 512 + tid] : 0;
    s[tid] = v;
    __syncthreads();
    for (int d = 1; d < 512; d <<= 1) {
        int t = (tid >= d) ? s[tid - d] : 0;
        __syncthreads();
        s[tid] += t;
        __syncthreads();
    }
    if (tid < NB_SCAN) bsum[br * 512 + tid] = s[tid] - v;
}

// Finalize: off2 = {start, start+deg} (one 8B record: kills one dependent
// load in gather/final2), seed cur.
__global__ void k_scan3(const int* __restrict__ off, const int* __restrict__ bsum,
                        const int* __restrict__ cnt, int2* __restrict__ off2,
                        int* __restrict__ cur) {
    int br = blockIdx.x / NB_SCAN;
    int blk = blockIdx.x % NB_SCAN;
    int i = blk * 256 + threadIdx.x;
    if (i < NN) {
        int o = off[br * NN + i] + bsum[br * 512 + blk];
        int2 pr;
        pr.x = o;
        pr.y = o + cnt[br * NN + i];
        off2[br * NN + i] = pr;
        cur[br * NN + i] = o;
    }
}

// Scatter packed edge record {src, coef} — one 8B store per edge.
__global__ void k_scatter(const int* __restrict__ ei, const int* __restrict__ vei,
                          const float* __restrict__ dinv, int* __restrict__ cur,
                          int2* __restrict__ ent) {
    int t = blockIdx.x * blockDim.x + threadIdx.x;
    if (t >= 2 * NE) return;
    int br = t >= NE;
    int e = t - br * NE;
    const int* S = br ? vei : ei;
    int s = S[e], d = S[NE + e];
    int pos = atomicAdd(&cur[br * NN + d], 1);
    int2 rec;
    rec.x = s;
    rec.y = __float_as_int(dinv[br * NN + s] * dinv[br * NN + d]);
    ent[br * NE + pos] = rec;
}

// Fused gather + layer-1 epilogue. 2 nodes per wave (32 lanes x uint2 each).
// Clamped 4-wide edge batches; ent has +8 rec padding. (R0-verified; off2 swap.)
__global__ void k_gather_ep(const ushort* __restrict__ H, const float* __restrict__ dinv,
                            const int2* __restrict__ off2,
                            const int2* __restrict__ ent,
                            const float* __restrict__ b1, const float* __restrict__ bv1,
                            const float* __restrict__ W2, const float* __restrict__ Wv2,
                            float* __restrict__ z) {
    int wid = threadIdx.x >> 6;
    int lane = threadIdx.x & 63;
    int half = lane >> 5;
    int l = lane & 31;
    int task = blockIdx.x * 8 + wid * 2 + half;
    int br = task >= NN;
    int n = task - br * NN;

    const int2* en = ent + br * NE;
    size_t hoff = (size_t)br * 128;

    float dv = dinv[br * NN + n];
    uint2 u = *(const uint2*)(H + (size_t)n * 256 + hoff + l * 4);
    float c = dv * dv;
    float a0 = bf2f(u.x & 0xffffu) * c, a1 = bf2f(u.x >> 16) * c;
    float a2 = bf2f(u.y & 0xffffu) * c, a3 = bf2f(u.y >> 16) * c;

    int2 pr = off2[br * NN + n];
    int p0 = pr.x, p1 = pr.y;
    for (int p = p0; p < p1; p += 4) {
        int2 e0 = en[p], e1 = en[p + 1], e2 = en[p + 2], e3 = en[p + 3];
        int s0 = e0.x;
        int s1 = (p + 1 < p1) ? e1.x : n;
        int s2 = (p + 2 < p1) ? e2.x : n;
        int s3 = (p + 3 < p1) ? e3.x : n;
        float c0 = __int_as_float(e0.y);
        float c1 = (p + 1 < p1) ? __int_as_float(e1.y) : 0.f;
        float c2 = (p + 2 < p1) ? __int_as_float(e2.y) : 0.f;
        float c3 = (p + 3 < p1) ? __int_as_float(e3.y) : 0.f;
        uint2 v0 = *(const uint2*)(H + (size_t)s0 * 256 + hoff + l * 4);
        uint2 v1 = *(const uint2*)(H + (size_t)s1 * 256 + hoff + l * 4);
        uint2 v2 = *(const uint2*)(H + (size_t)s2 * 256 + hoff + l * 4);
        uint2 v3 = *(const uint2*)(H + (size_t)s3 * 256 + hoff + l * 4);
        a0 += bf2f(v0.x & 0xffffu) * c0; a1 += bf2f(v0.x >> 16) * c0;
        a2 += bf2f(v0.y & 0xffffu) * c0; a3 += bf2f(v0.y >> 16) * c0;
        a0 += bf2f(v1.x & 0xffffu) * c1; a1 += bf2f(v1.x >> 16) * c1;
        a2 += bf2f(v1.y & 0xffffu) * c1; a3 += bf2f(v1.y >> 16) * c1;
        a0 += bf2f(v2.x & 0xffffu) * c2; a1 += bf2f(v2.x >> 16) * c2;
        a2 += bf2f(v2.y & 0xffffu) * c2; a3 += bf2f(v2.y >> 16) * c2;
        a0 += bf2f(v3.x & 0xffffu) * c3; a1 += bf2f(v3.x >> 16) * c3;
        a2 += bf2f(v3.y & 0xffffu) * c3; a3 += bf2f(v3.y >> 16) * c3;
    }

    const float* bb = br ? bv1 : b1;
    const float* ww = br ? Wv2 : W2;
    float4 b4 = *(const float4*)&bb[l * 4];
    float4 w4 = *(const float4*)&ww[l * 4];
    float part = fmaxf(a0 + b4.x, 0.f) * w4.x + fmaxf(a1 + b4.y, 0.f) * w4.y
               + fmaxf(a2 + b4.z, 0.f) * w4.z + fmaxf(a3 + b4.w, 0.f) * w4.w;
#pragma unroll
    for (int o = 16; o > 0; o >>= 1) part += __shfl_down(part, o, 32);
    if (l == 0) z[br * NN + n] = part;
}

// Layer-2 aggregation + LDS-batched y reduction (batch is sorted).
// Clamped 4-wide z-walk for MLP. (R0-verified; off2 swap.)
__global__ void k_final2(const float* __restrict__ z, const float* __restrict__ dinv,
                         const int2* __restrict__ off2,
                         const int2* __restrict__ ent,
                         const float* __restrict__ b2, const float* __restrict__ bv2,
                         const int* __restrict__ batch, float* __restrict__ y) {
    __shared__ float ybuf[256];
    __shared__ int gbase_s;
    int br = blockIdx.x >= NB_SCAN;
    int nb = blockIdx.x - br * NB_SCAN;
    int tid = threadIdx.x;
    ybuf[tid] = 0.f;
    if (tid == 0) gbase_s = batch[nb * 256];
    __syncthreads();
    int gbase = gbase_s;
    int n = nb * 256 + tid;
    if (n < NN) {
        const int2* en = ent + br * NE;
        float dv = dinv[br * NN + n];
        float acc = z[br * NN + n] * dv * dv;
        int2 pr = off2[br * NN + n];
        int p1 = pr.y;
        for (int p = pr.x; p < p1; p += 4) {
            int2 e0 = en[p], e1 = en[p + 1], e2 = en[p + 2], e3 = en[p + 3];
            int s0 = e0.x;
            int s1 = (p + 1 < p1) ? e1.x : n;
            int s2 = (p + 2 < p1) ? e2.x : n;
            int s3 = (p + 3 < p1) ? e3.x : n;
            float c0 = __int_as_float(e0.y);
            float c1 = (p + 1 < p1) ? __int_as_float(e1.y) : 0.f;
            float c2 = (p + 2 < p1) ? __int_as_float(e2.y) : 0.f;
            float c3 = (p + 3 < p1) ? __int_as_float(e3.y) : 0.f;
            acc += c0 * z[br * NN + s0] + c1 * z[br * NN + s1]
                 + c2 * z[br * NN + s2] + c3 * z[br * NN + s3];
        }
        acc += br ? bv2[0] : b2[0];
        int gi = batch[n] - gbase;
        if (gi < 256) atomicAdd(&ybuf[gi], acc);
        else atomicAdd(&y[batch[n]], acc);
    }
    __syncthreads();
    float v = ybuf[tid];
    if (v != 0.f) atomicAdd(&y[gbase + tid], v);
}

extern "C" void kernel_launch(void* const* d_in, const int* in_sizes, int n_in,
                              void* d_out, int out_size, void* d_ws, size_t ws_size,
                              hipStream_t stream) {
    const int*   tok   = (const int*)d_in[0];
    const float* pe    = (const float*)d_in[1];
    const int*   ei    = (const int*)d_in[2];
    const int*   vei   = (const int*)d_in[3];
    const int*   batch = (const int*)d_in[4];
    const float* embed = (const float*)d_in[5];
    const float* Wtr   = (const float*)d_in[6];
    const float* bt    = (const float*)d_in[7];
    const float* W1    = (const float*)d_in[8];
    const float* b1    = (const float*)d_in[9];
    const float* W2    = (const float*)d_in[10];
    const float* b2    = (const float*)d_in[11];
    const float* Wv1   = (const float*)d_in[12];
    const float* bv1   = (const float*)d_in[13];
    const float* Wv2   = (const float*)d_in[14];
    const float* bv2   = (const float*)d_in[15];

    float* y = (float*)d_out;       // [NG]
    float* x = y + NG;              // [NN*HD], output 1

    char* w = (char*)d_ws;
    ushort* H    = (ushort*)w;               w += (size_t)NN * 256 * 2;
    ushort* Wcat = (ushort*)w;               w += 256 * 128 * 2;
    float*  dinv = (float*)w;                w += 2 * NN * 4;
    float*  z    = (float*)w;                w += 2 * NN * 4;
    int*    cnt  = (int*)w;                  w += 2 * NN * 4;
    int*    off  = (int*)w;                  w += 2 * NN * 4;
    int*    cur  = (int*)w;                  w += 2 * NN * 4;
    int2*   off2 = (int2*)w;                 w += (size_t)2 * NN * 8;
    int2*   ent  = (int2*)w;                 w += (size_t)(2 * NE + 8) * 8;  // +pad
    int*    bsum = (int*)w;                  w += 2 * 512 * 4;

    k_prep0<<<NBW + NBZ, 256, 0, stream>>>(W1, Wv1, Wcat, cnt);
    k_front_gemm<<<NBF + NBD, 256, 0, stream>>>(tok, pe, embed, Wtr, bt, x,
                                                Wcat, H, ei, vei, cnt);
    k_scan1<<<2 * NB_SCAN, 256, 0, stream>>>(cnt, off, bsum, dinv, y);
    k_scan2<<<2, 512, 0, stream>>>(bsum);
    k_scan3<<<2 * NB_SCAN, 256, 0, stream>>>(off, bsum, cnt, off2, cur);
    k_scatter<<<NBD, 256, 0, stream>>>(ei, vei, dinv, cur, ent);
    k_gather_ep<<<2 * NN / 8, 256, 0, stream>>>(H, dinv, off2, ent,
                                                b1, bv1, W2, Wv2, z);
    k_final2<<<2 * NB_SCAN, 256, 0, stream>>>(z, dinv, off2, ent,
                                              b2, bv2, batch, y);
}